// Round 1
// baseline (117.655 us; speedup 1.0000x reference)
//
#include <hip/hip_runtime.h>
#include <hip/hip_bf16.h>

#define NB 128
#define NN 2048
#define DEG 16
#define EMBD 16
#define DD 4
#define NL 4
#define OBSD 6154
#define HID 45
#define NOUT 15

__device__ __forceinline__ float frcp(float v) { return __builtin_amdgcn_rcpf(v); }

__device__ __forceinline__ void ln4(const float* p, const float* g, const float* bb, float* o) {
    float m = 0.25f * (p[0] + p[1] + p[2] + p[3]);
    float var = 0.f;
#pragma unroll
    for (int j = 0; j < 4; ++j) { float d = p[j] - m; var += d * d; }
    var *= 0.25f;
    float rs = rsqrtf(var + 1e-5f);
#pragma unroll
    for (int j = 0; j < 4; ++j) o[j] = g[j] * (p[j] - m) * rs + bb[j];
}

__global__ __launch_bounds__(1024) void gat_kernel(
    const float* __restrict__ x, const int* __restrict__ src,
    const int* __restrict__ agent_nodes,
    const float* __restrict__ We, const float* __restrict__ be,
    const float* __restrict__ Wq, const float* __restrict__ bq,
    const float* __restrict__ Wk, const float* __restrict__ bk,
    const float* __restrict__ Wv, const float* __restrict__ bv,
    const float* __restrict__ Wo, const float* __restrict__ bo,
    const float* __restrict__ ln1_g, const float* __restrict__ ln1_b,
    const float* __restrict__ W1, const float* __restrict__ b1,
    const float* __restrict__ W2, const float* __restrict__ b2,
    const float* __restrict__ ln2_g, const float* __restrict__ ln2_b,
    float* __restrict__ gat_out)
{
    __shared__ float kv[NN * 8];   // k[4], v[4] interleaved per node: 64 KiB
    const int b = blockIdx.x;
    const int tid = threadIdx.x;

    float h[2][4];

    // --- node embedding: h = x @ We + be ---
#pragma unroll
    for (int u = 0; u < 2; ++u) {
        const int n = tid + u * 1024;
        const float4* xr = reinterpret_cast<const float4*>(x + ((size_t)b * NN + n) * EMBD);
        float xv[16];
#pragma unroll
        for (int t4 = 0; t4 < 4; ++t4) {
            float4 t = xr[t4];
            xv[t4 * 4 + 0] = t.x; xv[t4 * 4 + 1] = t.y;
            xv[t4 * 4 + 2] = t.z; xv[t4 * 4 + 3] = t.w;
        }
#pragma unroll
        for (int j = 0; j < 4; ++j) {
            float s = be[j];
#pragma unroll
            for (int i = 0; i < 16; ++i) s += xv[i] * We[i * 4 + j];
            h[u][j] = s;
        }
    }

    for (int l = 0; l < NL; ++l) {
        float q[2][4];
        // --- q,k,v projection; k,v -> LDS ---
        {
            const float* wq = Wq + l * 16; const float* bql = bq + l * 4;
            const float* wk = Wk + l * 16; const float* bkl = bk + l * 4;
            const float* wv = Wv + l * 16; const float* bvl = bv + l * 4;
#pragma unroll
            for (int u = 0; u < 2; ++u) {
                const int n = tid + u * 1024;
                float kk[4], vv[4];
#pragma unroll
                for (int j = 0; j < 4; ++j) {
                    float sq = bql[j], sk = bkl[j], sv = bvl[j];
#pragma unroll
                    for (int i = 0; i < 4; ++i) {
                        sq += h[u][i] * wq[i * 4 + j];
                        sk += h[u][i] * wk[i * 4 + j];
                        sv += h[u][i] * wv[i * 4 + j];
                    }
                    q[u][j] = sq; kk[j] = sk; vv[j] = sv;
                }
                float4* kvp = reinterpret_cast<float4*>(&kv[n * 8]);
                kvp[0] = make_float4(kk[0], kk[1], kk[2], kk[3]);
                kvp[1] = make_float4(vv[0], vv[1], vv[2], vv[3]);
            }
        }
        __syncthreads();

        // --- attention (single-pass, no-max softmax) + Wo + LN1 + FFN + LN2 ---
        const float* wo = Wo + l * 16; const float* bol = bo + l * 4;
        const float* g1 = ln1_g + l * 4; const float* be1 = ln1_b + l * 4;
        const float* w1 = W1 + l * 32;  const float* b1l = b1 + l * 8;
        const float* w2 = W2 + l * 32;  const float* b2l = b2 + l * 4;
        const float* g2 = ln2_g + l * 4; const float* be2 = ln2_b + l * 4;
#pragma unroll
        for (int u = 0; u < 2; ++u) {
            const int n = tid + u * 1024;
            const int4* sp = reinterpret_cast<const int4*>(src + n * DEG);
            float z[4] = {0.f, 0.f, 0.f, 0.f};
            float wa[4] = {0.f, 0.f, 0.f, 0.f};
#pragma unroll
            for (int eb = 0; eb < 4; ++eb) {
                int4 s4 = sp[eb];
                int sis[4] = {s4.x, s4.y, s4.z, s4.w};
#pragma unroll
                for (int e = 0; e < 4; ++e) {
                    const float4 kk = *reinterpret_cast<const float4*>(&kv[sis[e] * 8]);
                    const float4 vv = *reinterpret_cast<const float4*>(&kv[sis[e] * 8 + 4]);
                    float p0 = __expf(q[u][0] * kk.x);
                    float p1 = __expf(q[u][1] * kk.y);
                    float p2 = __expf(q[u][2] * kk.z);
                    float p3 = __expf(q[u][3] * kk.w);
                    z[0] += p0; z[1] += p1; z[2] += p2; z[3] += p3;
                    wa[0] += p0 * vv.x; wa[1] += p1 * vv.y;
                    wa[2] += p2 * vv.z; wa[3] += p3 * vv.w;
                }
            }
            float msg[4];
#pragma unroll
            for (int j = 0; j < 4; ++j) msg[j] = wa[j] * frcp(z[j] + 1e-6f);
            float pre[4];
#pragma unroll
            for (int j = 0; j < 4; ++j) {
                float s = bol[j];
#pragma unroll
                for (int i = 0; i < 4; ++i) s += msg[i] * wo[i * 4 + j];
                pre[j] = h[u][j] + s;
            }
            float hn[4];
            ln4(pre, g1, be1, hn);
            float mid[8];
#pragma unroll
            for (int j = 0; j < 8; ++j) {
                float s = b1l[j];
#pragma unroll
                for (int i = 0; i < 4; ++i) s += hn[i] * w1[i * 8 + j];
                mid[j] = fmaxf(s, 0.f);
            }
            float pre2[4];
#pragma unroll
            for (int j = 0; j < 4; ++j) {
                float s = b2l[j];
#pragma unroll
                for (int i = 0; i < 8; ++i) s += mid[i] * w2[i * 4 + j];
                pre2[j] = hn[j] + s;
            }
            ln4(pre2, g2, be2, h[u]);
        }
        __syncthreads();
    }

    const int agent = agent_nodes[b];
#pragma unroll
    for (int u = 0; u < 2; ++u) {
        if (tid + u * 1024 == agent) {
#pragma unroll
            for (int j = 0; j < 4; ++j) gat_out[b * 4 + j] = h[u][j];
        }
    }
}

__global__ __launch_bounds__(512) void mlp_kernel(
    const float* __restrict__ obs, const float* __restrict__ gat,
    const float* __restrict__ oW1, const float* __restrict__ ob1,
    const float* __restrict__ oW2, const float* __restrict__ ob2,
    const float* __restrict__ oW3, const float* __restrict__ ob3,
    float* __restrict__ out)
{
    __shared__ float red[8][HID];
    __shared__ float hm1[HID];
    __shared__ float hm2[HID];
    const int b = blockIdx.x;
    const int tid = threadIdx.x;
    const int wave = tid >> 6, lane = tid & 63;
    const float* ob = obs + (size_t)b * OBSD;

    if (lane < HID) {
        float a0 = 0.f, a1 = 0.f, a2 = 0.f, a3 = 0.f;
        const int i0 = wave * 770;
        const int i1 = (i0 + 770 < OBSD) ? (i0 + 770) : OBSD;
        int i = i0;
        for (; i + 4 <= i1; i += 4) {
            a0 += ob[i + 0] * oW1[(size_t)(i + 4) * HID + lane];
            a1 += ob[i + 1] * oW1[(size_t)(i + 5) * HID + lane];
            a2 += ob[i + 2] * oW1[(size_t)(i + 6) * HID + lane];
            a3 += ob[i + 3] * oW1[(size_t)(i + 7) * HID + lane];
        }
        for (; i < i1; ++i) a0 += ob[i] * oW1[(size_t)(i + 4) * HID + lane];
        if (wave == 0) {
#pragma unroll
            for (int k = 0; k < 4; ++k) a1 += gat[b * 4 + k] * oW1[k * HID + lane];
        }
        red[wave][lane] = a0 + a1 + a2 + a3;
    }
    __syncthreads();
    if (tid < HID) {
        float s = ob1[tid];
#pragma unroll
        for (int w = 0; w < 8; ++w) s += red[w][tid];
        hm1[tid] = tanhf(s);
    }
    __syncthreads();
    if (tid < HID) {
        float s = ob2[tid];
        for (int k = 0; k < HID; ++k) s += hm1[k] * oW2[k * HID + tid];
        hm2[tid] = tanhf(s);
    }
    __syncthreads();
    if (tid < NOUT) {
        float s = ob3[tid];
        for (int k = 0; k < HID; ++k) s += hm2[k] * oW3[k * NOUT + tid];
        out[(size_t)b * NOUT + tid] = s;
    }
}

extern "C" void kernel_launch(void* const* d_in, const int* in_sizes, int n_in,
                              void* d_out, int out_size, void* d_ws, size_t ws_size,
                              hipStream_t stream) {
    const float* x      = (const float*)d_in[0];
    const float* obs    = (const float*)d_in[1];
    const int*   src    = (const int*)d_in[2];
    /* d_in[3] = dst: structurally repeat(arange(N), DEG) — not needed */
    const int*   agent  = (const int*)d_in[4];
    const float* We     = (const float*)d_in[5];
    const float* be     = (const float*)d_in[6];
    const float* Wq     = (const float*)d_in[7];
    const float* bq     = (const float*)d_in[8];
    const float* Wk     = (const float*)d_in[9];
    const float* bk     = (const float*)d_in[10];
    const float* Wv     = (const float*)d_in[11];
    const float* bv     = (const float*)d_in[12];
    const float* Wo     = (const float*)d_in[13];
    const float* bo     = (const float*)d_in[14];
    const float* ln1_g  = (const float*)d_in[15];
    const float* ln1_b  = (const float*)d_in[16];
    const float* W1     = (const float*)d_in[17];
    const float* b1     = (const float*)d_in[18];
    const float* W2     = (const float*)d_in[19];
    const float* b2     = (const float*)d_in[20];
    const float* ln2_g  = (const float*)d_in[21];
    const float* ln2_b  = (const float*)d_in[22];
    const float* oW1    = (const float*)d_in[23];
    const float* ob1    = (const float*)d_in[24];
    const float* oW2    = (const float*)d_in[25];
    const float* ob2    = (const float*)d_in[26];
    const float* oW3    = (const float*)d_in[27];
    const float* ob3    = (const float*)d_in[28];

    float* out     = (float*)d_out;
    float* gat_out = (float*)d_ws;   // [128][4] agent-node features

    gat_kernel<<<NB, 1024, 0, stream>>>(x, src, agent, We, be, Wq, bq, Wk, bk, Wv, bv,
                                        Wo, bo, ln1_g, ln1_b, W1, b1, W2, b2,
                                        ln2_g, ln2_b, gat_out);
    mlp_kernel<<<NB, 512, 0, stream>>>(obs, gat_out, oW1, ob1, oW2, ob2, oW3, ob3, out);
}

// Round 2
// 76.052 us; speedup vs baseline: 1.5470x; 1.5470x over previous
//
#include <hip/hip_runtime.h>
#include <hip/hip_bf16.h>

#define NB 128
#define NN 2048
#define DEG 16
#define EMBD 16
#define NL 4
#define OBSD 6154
#define HID 45
#define NOUT 15
#define KS 16
#define CH 385   // ceil(OBSD / KS)

__device__ __forceinline__ float frcp(float v) { return __builtin_amdgcn_rcpf(v); }

__device__ __forceinline__ uint32_t pk_bf16(float a, float b) {
    // round-to-nearest-even bf16 pack (no NaN handling; values are tame)
    uint32_t ua = __float_as_uint(a); ua += 0x7fffu + ((ua >> 16) & 1u);
    uint32_t ub = __float_as_uint(b); ub += 0x7fffu + ((ub >> 16) & 1u);
    return (ua >> 16) | (ub & 0xffff0000u);
}
__device__ __forceinline__ float lo_bf(uint32_t u) { return __uint_as_float(u << 16); }
__device__ __forceinline__ float hi_bf(uint32_t u) { return __uint_as_float(u & 0xffff0000u); }

__device__ __forceinline__ void ln4(const float* p, const float* g, const float* bb, float* o) {
    float m = 0.25f * (p[0] + p[1] + p[2] + p[3]);
    float var = 0.f;
#pragma unroll
    for (int j = 0; j < 4; ++j) { float d = p[j] - m; var += d * d; }
    var *= 0.25f;
    float rs = rsqrtf(var + 1e-5f);
#pragma unroll
    for (int j = 0; j < 4; ++j) o[j] = g[j] * (p[j] - m) * rs + bb[j];
}

__global__ __launch_bounds__(1024) void gat_kernel(
    const float* __restrict__ x, const int* __restrict__ src,
    const int* __restrict__ agent_nodes,
    const float* __restrict__ We, const float* __restrict__ be,
    const float* __restrict__ Wq, const float* __restrict__ bq,
    const float* __restrict__ Wk, const float* __restrict__ bk,
    const float* __restrict__ Wv, const float* __restrict__ bv,
    const float* __restrict__ Wo, const float* __restrict__ bo,
    const float* __restrict__ ln1_g, const float* __restrict__ ln1_b,
    const float* __restrict__ W1, const float* __restrict__ b1,
    const float* __restrict__ W2, const float* __restrict__ b2,
    const float* __restrict__ ln2_g, const float* __restrict__ ln2_b,
    float* __restrict__ gat_out)
{
    __shared__ uint4 kv[NN];   // k[4],v[4] as 8x bf16 per node: 32 KiB
    const int b = blockIdx.x;
    const int tid = threadIdx.x;

    float h[2][4];

    // --- node embedding: h = x @ We + be ---
#pragma unroll
    for (int u = 0; u < 2; ++u) {
        const int n = tid + u * 1024;
        const float4* xr = reinterpret_cast<const float4*>(x + ((size_t)b * NN + n) * EMBD);
        float xv[16];
#pragma unroll
        for (int t4 = 0; t4 < 4; ++t4) {
            float4 t = xr[t4];
            xv[t4 * 4 + 0] = t.x; xv[t4 * 4 + 1] = t.y;
            xv[t4 * 4 + 2] = t.z; xv[t4 * 4 + 3] = t.w;
        }
#pragma unroll
        for (int j = 0; j < 4; ++j) {
            float s = be[j];
#pragma unroll
            for (int i = 0; i < 16; ++i) s += xv[i] * We[i * 4 + j];
            h[u][j] = s;
        }
    }

    for (int l = 0; l < NL; ++l) {
        float q[2][4];
        {
            const float* wq = Wq + l * 16; const float* bql = bq + l * 4;
            const float* wk = Wk + l * 16; const float* bkl = bk + l * 4;
            const float* wv = Wv + l * 16; const float* bvl = bv + l * 4;
#pragma unroll
            for (int u = 0; u < 2; ++u) {
                const int n = tid + u * 1024;
                float kk[4], vv[4];
#pragma unroll
                for (int j = 0; j < 4; ++j) {
                    float sq = bql[j], sk = bkl[j], sv = bvl[j];
#pragma unroll
                    for (int i = 0; i < 4; ++i) {
                        sq += h[u][i] * wq[i * 4 + j];
                        sk += h[u][i] * wk[i * 4 + j];
                        sv += h[u][i] * wv[i * 4 + j];
                    }
                    q[u][j] = sq; kk[j] = sk; vv[j] = sv;
                }
                kv[n] = make_uint4(pk_bf16(kk[0], kk[1]), pk_bf16(kk[2], kk[3]),
                                   pk_bf16(vv[0], vv[1]), pk_bf16(vv[2], vv[3]));
            }
        }
        __syncthreads();

        const float* wo = Wo + l * 16; const float* bol = bo + l * 4;
        const float* g1 = ln1_g + l * 4; const float* be1 = ln1_b + l * 4;
        const float* w1 = W1 + l * 32;  const float* b1l = b1 + l * 8;
        const float* w2 = W2 + l * 32;  const float* b2l = b2 + l * 4;
        const float* g2 = ln2_g + l * 4; const float* be2 = ln2_b + l * 4;
#pragma unroll
        for (int u = 0; u < 2; ++u) {
            const int n = tid + u * 1024;
            const int4* sp = reinterpret_cast<const int4*>(src + n * DEG);
            float z[4] = {0.f, 0.f, 0.f, 0.f};
            float wa[4] = {0.f, 0.f, 0.f, 0.f};
#pragma unroll
            for (int eb = 0; eb < 4; ++eb) {
                int4 s4 = sp[eb];
                int sis[4] = {s4.x, s4.y, s4.z, s4.w};
#pragma unroll
                for (int e = 0; e < 4; ++e) {
                    const uint4 t = kv[sis[e]];
                    float p0 = __expf(q[u][0] * lo_bf(t.x));
                    float p1 = __expf(q[u][1] * hi_bf(t.x));
                    float p2 = __expf(q[u][2] * lo_bf(t.y));
                    float p3 = __expf(q[u][3] * hi_bf(t.y));
                    z[0] += p0; z[1] += p1; z[2] += p2; z[3] += p3;
                    wa[0] += p0 * lo_bf(t.z); wa[1] += p1 * hi_bf(t.z);
                    wa[2] += p2 * lo_bf(t.w); wa[3] += p3 * hi_bf(t.w);
                }
            }
            float msg[4];
#pragma unroll
            for (int j = 0; j < 4; ++j) msg[j] = wa[j] * frcp(z[j] + 1e-6f);
            float pre[4];
#pragma unroll
            for (int j = 0; j < 4; ++j) {
                float s = bol[j];
#pragma unroll
                for (int i = 0; i < 4; ++i) s += msg[i] * wo[i * 4 + j];
                pre[j] = h[u][j] + s;
            }
            float hn[4];
            ln4(pre, g1, be1, hn);
            float mid[8];
#pragma unroll
            for (int j = 0; j < 8; ++j) {
                float s = b1l[j];
#pragma unroll
                for (int i = 0; i < 4; ++i) s += hn[i] * w1[i * 8 + j];
                mid[j] = fmaxf(s, 0.f);
            }
            float pre2[4];
#pragma unroll
            for (int j = 0; j < 4; ++j) {
                float s = b2l[j];
#pragma unroll
                for (int i = 0; i < 8; ++i) s += mid[i] * w2[i * 4 + j];
                pre2[j] = hn[j] + s;
            }
            ln4(pre2, g2, be2, h[u]);
        }
        __syncthreads();
    }

    const int agent = agent_nodes[b];
#pragma unroll
    for (int u = 0; u < 2; ++u) {
        if (tid + u * 1024 == agent) {
#pragma unroll
            for (int j = 0; j < 4; ++j) gat_out[b * 4 + j] = h[u][j];
        }
    }
}

// --- MLP stage 1: split-K partial dot products for fc1 ---
__global__ __launch_bounds__(256) void mlp1_kernel(
    const float* __restrict__ obs, const float* __restrict__ gat,
    const float* __restrict__ oW1, float* __restrict__ partial)
{
    __shared__ float red[4][HID];
    const int blk = blockIdx.x;
    const int b = blk >> 4;       // / KS
    const int ks = blk & (KS - 1);
    const int tid = threadIdx.x;
    const int w = tid >> 6, lane = tid & 63;
    const float* ob = obs + (size_t)b * OBSD;

    const int c0 = ks * CH;
    const int c1 = min(c0 + CH, OBSD);
    const int wl = (c1 - c0 + 3) >> 2;
    const int s0 = c0 + w * wl;
    const int s1 = min(s0 + wl, c1);

    if (lane < HID) {
        float a0 = 0.f, a1 = 0.f, a2 = 0.f, a3 = 0.f;
        int i = s0;
        for (; i + 4 <= s1; i += 4) {
            a0 += ob[i + 0] * oW1[(size_t)(i + 4) * HID + lane];
            a1 += ob[i + 1] * oW1[(size_t)(i + 5) * HID + lane];
            a2 += ob[i + 2] * oW1[(size_t)(i + 6) * HID + lane];
            a3 += ob[i + 3] * oW1[(size_t)(i + 7) * HID + lane];
        }
        for (; i < s1; ++i) a0 += ob[i] * oW1[(size_t)(i + 4) * HID + lane];
        if (ks == 0 && w == 0) {
#pragma unroll
            for (int k = 0; k < 4; ++k) a1 += gat[b * 4 + k] * oW1[k * HID + lane];
        }
        red[w][lane] = a0 + a1 + a2 + a3;
    }
    __syncthreads();
    if (tid < HID) {
        partial[(size_t)blk * HID + tid] =
            red[0][tid] + red[1][tid] + red[2][tid] + red[3][tid];
    }
}

// --- MLP stage 2: reduce partials, tanh, fc2, tanh, fc3 ---
__global__ __launch_bounds__(64) void mlp2_kernel(
    const float* __restrict__ partial,
    const float* __restrict__ ob1,
    const float* __restrict__ oW2, const float* __restrict__ ob2,
    const float* __restrict__ oW3, const float* __restrict__ ob3,
    float* __restrict__ out)
{
    __shared__ float hm1[HID], hm2[HID];
    const int b = blockIdx.x;
    const int tid = threadIdx.x;
    if (tid < HID) {
        float s = ob1[tid];
        const float* p = partial + (size_t)b * KS * HID;
#pragma unroll
        for (int ks = 0; ks < KS; ++ks) s += p[ks * HID + tid];
        hm1[tid] = tanhf(s);
    }
    __syncthreads();
    if (tid < HID) {
        float s = ob2[tid];
        for (int k = 0; k < HID; ++k) s += hm1[k] * oW2[k * HID + tid];
        hm2[tid] = tanhf(s);
    }
    __syncthreads();
    if (tid < NOUT) {
        float s = ob3[tid];
        for (int k = 0; k < HID; ++k) s += hm2[k] * oW3[k * NOUT + tid];
        out[(size_t)b * NOUT + tid] = s;
    }
}

extern "C" void kernel_launch(void* const* d_in, const int* in_sizes, int n_in,
                              void* d_out, int out_size, void* d_ws, size_t ws_size,
                              hipStream_t stream) {
    const float* x      = (const float*)d_in[0];
    const float* obs    = (const float*)d_in[1];
    const int*   src    = (const int*)d_in[2];
    /* d_in[3] = dst: structurally repeat(arange(N), DEG) — not needed */
    const int*   agent  = (const int*)d_in[4];
    const float* We     = (const float*)d_in[5];
    const float* be     = (const float*)d_in[6];
    const float* Wq     = (const float*)d_in[7];
    const float* bq     = (const float*)d_in[8];
    const float* Wk     = (const float*)d_in[9];
    const float* bk     = (const float*)d_in[10];
    const float* Wv     = (const float*)d_in[11];
    const float* bv     = (const float*)d_in[12];
    const float* Wo     = (const float*)d_in[13];
    const float* bo     = (const float*)d_in[14];
    const float* ln1_g  = (const float*)d_in[15];
    const float* ln1_b  = (const float*)d_in[16];
    const float* W1     = (const float*)d_in[17];
    const float* b1     = (const float*)d_in[18];
    const float* W2     = (const float*)d_in[19];
    const float* b2     = (const float*)d_in[20];
    const float* ln2_g  = (const float*)d_in[21];
    const float* ln2_b  = (const float*)d_in[22];
    const float* oW1    = (const float*)d_in[23];
    const float* ob1    = (const float*)d_in[24];
    const float* oW2    = (const float*)d_in[25];
    const float* ob2    = (const float*)d_in[26];
    const float* oW3    = (const float*)d_in[27];
    const float* ob3    = (const float*)d_in[28];

    float* out     = (float*)d_out;
    float* gat_out = (float*)d_ws;                    // [128][4]
    float* partial = (float*)d_ws + 512;              // [128][KS][45]

    gat_kernel<<<NB, 1024, 0, stream>>>(x, src, agent, We, be, Wq, bq, Wk, bk, Wv, bv,
                                        Wo, bo, ln1_g, ln1_b, W1, b1, W2, b2,
                                        ln2_g, ln2_b, gat_out);
    mlp1_kernel<<<NB * KS, 256, 0, stream>>>(obs, gat_out, oW1, partial);
    mlp2_kernel<<<NB, 64, 0, stream>>>(partial, ob1, oW2, ob2, oW3, ob3, out);
}